// Round 19
// baseline (236.666 us; speedup 1.0000x reference)
//
#include <hip/hip_runtime.h>

// GNN surrogate — SINGLE-DISPATCH fused kernel (r19).
// Each block redundantly computes the (tiny, 46 KB) prep into its own LDS:
// adj fp32 -> f16 swizzled tiles, folded weights Meff/W1eff in fp32 (exact
// r18 prep math), v/biases/u. One __syncthreads(), then the r17/r18
// all-register K=16 MFMA chain (verified: C-frag [row=quad*4+r][col=lane&15]
// == operand [k=quad*4+j][m|n=lane&15]; pk4'd C-frag IS the next operand).
// Removes the prep dispatch entirely — probes whether the constant ~75 us
// bench-vs-kernel gap (r7..r18) is the two-dispatch graph structure.
// Folds (exact): M_l = W2[l]@W1[l+1] (adj row-normalized -> biases commute
// through aggregation), lift into W1eff (K=3 pad 16), v=colmean(adj),
// u=W2[2]@W_ro, cp=(b2[2]·W_ro)*sum(v)+b_ro.

typedef _Float16 f16;
typedef __attribute__((ext_vector_type(4))) _Float16 half4;
typedef __attribute__((ext_vector_type(2))) __fp16 fp16x2;
typedef __attribute__((ext_vector_type(4))) float f32x4;

namespace {
constexpr int N = 128, H = 32;
}

static __device__ __forceinline__ half4 pk4(float a, float b, float c, float d) {
  union { half4 v; fp16x2 h[2]; } u;
  u.h[0] = __builtin_amdgcn_cvt_pkrtz(a, b);
  u.h[1] = __builtin_amdgcn_cvt_pkrtz(c, d);
  return u.v;
}
static __device__ __forceinline__ half4 relupk(f32x4 c) {
  const half4 z = {};
  return __builtin_elementwise_max(pk4(c[0], c[1], c[2], c[3]), z);
}
static __device__ __forceinline__ half4 pkc(f32x4 c) {
  return pk4(c[0], c[1], c[2], c[3]);
}

#define MF(A, B, C) __builtin_amdgcn_mfma_f32_16x16x16f16((A), (B), (C), 0, 0, 0)

__global__ __launch_bounds__(256, 2)
void gnn_fused(const float* __restrict__ x,
               const float* __restrict__ adj,
               const float* __restrict__ W_lift,
               const float* __restrict__ b_lift,
               const float* __restrict__ W1,
               const float* __restrict__ b1,
               const float* __restrict__ W2,
               const float* __restrict__ b2,
               const float* __restrict__ W_ro,
               const float* __restrict__ b_ro,
               float* __restrict__ out) {
  __shared__ __align__(16) f16 adjl[16384];   // 32 KB swizzled adj tiles
  __shared__ float tmpW[3 * 1024];            // 12 KB folded weights (fp32)
  __shared__ float bial[96];                  // b0eff, c1, c2
  __shared__ float vl[128];                   // v
  __shared__ float ul[32];                    // u

  const int tid  = threadIdx.x;
  const int wave = tid >> 6;
  const int lane = tid & 63;
  const int lrow = lane & 15;
  const int quad = lane >> 4;
  const int b    = blockIdx.x * 4 + wave;

  // ================= cooperative per-block prep =================
  // adj -> f16 swizzled tiles: entry e=(g,p,lane): value[h*4+jj] =
  // adj[g*16+lr][(2p+h)*16 + q*4 + jj]
  for (int e = tid; e < 2048; e += 256) {
    const int g = e >> 8, p = (e >> 6) & 3, ln = e & 63;
    const int lr = ln & 15, q = ln >> 4;
    const float* src = adj + (g * 16 + lr) * N + (2 * p) * 16 + q * 4;
    const float4 f0 = *(const float4*)(src);
    const float4 f1 = *(const float4*)(src + 16);
    *(half4*)(adjl + e * 8)     = pk4(f0.x, f0.y, f0.z, f0.w);
    *(half4*)(adjl + e * 8 + 4) = pk4(f1.x, f1.y, f1.z, f1.w);
  }
  // folded weights (fp32, exact r18 prep math)
  for (int idx = tid; idx < 3 * H * H; idx += 256) {
    const int l = idx >> 10, rem = idx & 1023;
    const int k = rem >> 5, fo = rem & 31;
    float val = 0.f;
    if (l == 0) {
      if (k < 3)
        for (int c = 0; c < H; ++c) val += W_lift[k * H + c] * W1[c * H + fo];
    } else {
      const float* w2l = W2 + (l - 1) * H * H;
      const float* w1n = W1 + l * H * H;
      for (int c = 0; c < H; ++c) val += w2l[k * H + c] * w1n[c * H + fo];
    }
    tmpW[idx] = val;
  }
  if (tid < 128) {                       // v[j] = mean_i adj[i][j]
    float s = 0.f;
    for (int i = 0; i < N; ++i) s += adj[i * N + tid];
    vl[tid] = s * (1.0f / N);
  } else if (tid < 224) {                // biases: j=0..95, l=j>>5
    const int j = tid - 128;
    const int l = j >> 5, fo = j & 31;
    float s = b1[l * H + fo];
    if (l == 0) {
      for (int c = 0; c < H; ++c) s += b_lift[c] * W1[c * H + fo];
    } else {
      for (int c = 0; c < H; ++c) s += b2[(l - 1) * H + c] * W1[l * H * H + c * H + fo];
    }
    bial[j] = s;
  } else {                               // u[k] = W2[2][k,:]·W_ro
    const int k = tid - 224;
    float s = 0.f;
    for (int c = 0; c < H; ++c) s += W2[2 * H * H + k * H + c] * W_ro[c];
    ul[k] = s;
  }
  __syncthreads();

  // per-lane weight fragments (B-operand layout, f16) from fp32 LDS
#define LDM(l, t, tp)                                                        \
  pk4(tmpW[(l) * 1024 + ((t) * 16 + quad * 4 + 0) * 32 + (tp) * 16 + lrow],  \
      tmpW[(l) * 1024 + ((t) * 16 + quad * 4 + 1) * 32 + (tp) * 16 + lrow],  \
      tmpW[(l) * 1024 + ((t) * 16 + quad * 4 + 2) * 32 + (tp) * 16 + lrow],  \
      tmpW[(l) * 1024 + ((t) * 16 + quad * 4 + 3) * 32 + (tp) * 16 + lrow])
  const half4 w0   = LDM(0, 0, 0), w1   = LDM(0, 0, 1);
  const half4 m100 = LDM(1, 0, 0), m101 = LDM(1, 0, 1);
  const half4 m110 = LDM(1, 1, 0), m111 = LDM(1, 1, 1);
  const half4 m200 = LDM(2, 0, 0), m201 = LDM(2, 0, 1);
  const half4 m210 = LDM(2, 1, 0), m211 = LDM(2, 1, 1);
#undef LDM
  const float bb0l0 = bial[lrow],      bb1l0 = bial[16 + lrow];
  const float bb0l1 = bial[32 + lrow], bb1l1 = bial[48 + lrow];
  const float bb0l2 = bial[64 + lrow], bb1l2 = bial[80 + lrow];
  const float u0 = ul[lrow], u1 = ul[16 + lrow];

  const f32x4 zero = {0.f, 0.f, 0.f, 0.f};

  half4 tf00, tf01, tf10, tf11, tf20, tf21, tf30, tf31,
        tf40, tf41, tf50, tf51, tf60, tf61, tf70, tf71;
  half4 pf00, pf01, pf02, pf03, pf04, pf05, pf06, pf07,
        pf10, pf11, pf12, pf13, pf14, pf15, pf16, pf17;

  // ---- L0: T0[node][fout] = relu(x·W1eff + b0eff) ----
  {
    const f32x4 bi0 = {bb0l0, bb0l0, bb0l0, bb0l0};
    const f32x4 bi1 = {bb1l0, bb1l0, bb1l0, bb1l0};
#define L0G(g, TF0, TF1)                                                     \
    {                                                                        \
      half4 xa = {};                                                         \
      if (quad == 0) {                                                       \
        const float* xr = x + ((size_t)b * N + (g) * 16 + lrow) * 3;         \
        xa = pk4(xr[0], xr[1], xr[2], 0.f);                                  \
      }                                                                      \
      TF0 = relupk(MF(xa, w0, bi0));                                         \
      TF1 = relupk(MF(xa, w1, bi1));                                         \
    }
    L0G(0, tf00, tf01) L0G(1, tf10, tf11) L0G(2, tf20, tf21) L0G(3, tf30, tf31)
    L0G(4, tf40, tf41) L0G(5, tf50, tf51) L0G(6, tf60, tf61) L0G(7, tf70, tf71)
#undef L0G
  }

  // ---- G stage: p-outer / gi-inner, 16 independent acc chains (LDS adj) ----
#define GP(p, TA0, TA1, TB0, TB1)                                            \
  {                                                                          \
    const f16* bp = adjl + (((p) * 64) + lane) * 8;                          \
    const half4 h0g0 = *(const half4*)(bp + 0 * 2048);                       \
    const half4 h1g0 = *(const half4*)(bp + 0 * 2048 + 4);                   \
    const half4 h0g1 = *(const half4*)(bp + 1 * 2048);                       \
    const half4 h1g1 = *(const half4*)(bp + 1 * 2048 + 4);                   \
    const half4 h0g2 = *(const half4*)(bp + 2 * 2048);                       \
    const half4 h1g2 = *(const half4*)(bp + 2 * 2048 + 4);                   \
    const half4 h0g3 = *(const half4*)(bp + 3 * 2048);                       \
    const half4 h1g3 = *(const half4*)(bp + 3 * 2048 + 4);                   \
    const half4 h0g4 = *(const half4*)(bp + 4 * 2048);                       \
    const half4 h1g4 = *(const half4*)(bp + 4 * 2048 + 4);                   \
    const half4 h0g5 = *(const half4*)(bp + 5 * 2048);                       \
    const half4 h1g5 = *(const half4*)(bp + 5 * 2048 + 4);                   \
    const half4 h0g6 = *(const half4*)(bp + 6 * 2048);                       \
    const half4 h1g6 = *(const half4*)(bp + 6 * 2048 + 4);                   \
    const half4 h0g7 = *(const half4*)(bp + 7 * 2048);                       \
    const half4 h1g7 = *(const half4*)(bp + 7 * 2048 + 4);                   \
    A00 = MF(TA0, h0g0, A00); A01 = MF(TA1, h0g0, A01);                      \
    A10 = MF(TA0, h0g1, A10); A11 = MF(TA1, h0g1, A11);                      \
    A20 = MF(TA0, h0g2, A20); A21 = MF(TA1, h0g2, A21);                      \
    A30 = MF(TA0, h0g3, A30); A31 = MF(TA1, h0g3, A31);                      \
    A40 = MF(TA0, h0g4, A40); A41 = MF(TA1, h0g4, A41);                      \
    A50 = MF(TA0, h0g5, A50); A51 = MF(TA1, h0g5, A51);                      \
    A60 = MF(TA0, h0g6, A60); A61 = MF(TA1, h0g6, A61);                      \
    A70 = MF(TA0, h0g7, A70); A71 = MF(TA1, h0g7, A71);                      \
    A00 = MF(TB0, h1g0, A00); A01 = MF(TB1, h1g0, A01);                      \
    A10 = MF(TB0, h1g1, A10); A11 = MF(TB1, h1g1, A11);                      \
    A20 = MF(TB0, h1g2, A20); A21 = MF(TB1, h1g2, A21);                      \
    A30 = MF(TB0, h1g3, A30); A31 = MF(TB1, h1g3, A31);                      \
    A40 = MF(TB0, h1g4, A40); A41 = MF(TB1, h1g4, A41);                      \
    A50 = MF(TB0, h1g5, A50); A51 = MF(TB1, h1g5, A51);                      \
    A60 = MF(TB0, h1g6, A60); A61 = MF(TB1, h1g6, A61);                      \
    A70 = MF(TB0, h1g7, A70); A71 = MF(TB1, h1g7, A71);                      \
  }
#define GSTAGE()                                                             \
  {                                                                          \
    f32x4 A00 = zero, A01 = zero, A10 = zero, A11 = zero,                    \
          A20 = zero, A21 = zero, A30 = zero, A31 = zero,                    \
          A40 = zero, A41 = zero, A50 = zero, A51 = zero,                    \
          A60 = zero, A61 = zero, A70 = zero, A71 = zero;                    \
    GP(0, tf00, tf01, tf10, tf11)                                            \
    GP(1, tf20, tf21, tf30, tf31)                                            \
    GP(2, tf40, tf41, tf50, tf51)                                            \
    GP(3, tf60, tf61, tf70, tf71)                                            \
    pf00 = pkc(A00); pf10 = pkc(A01); pf01 = pkc(A10); pf11 = pkc(A11);      \
    pf02 = pkc(A20); pf12 = pkc(A21); pf03 = pkc(A30); pf13 = pkc(A31);      \
    pf04 = pkc(A40); pf14 = pkc(A41); pf05 = pkc(A50); pf15 = pkc(A51);      \
    pf06 = pkc(A60); pf16 = pkc(A61); pf07 = pkc(A70); pf17 = pkc(A71);      \
  }

  GSTAGE()   // G0

  // ---- L1: T1[node][fout'] = relu(P·Meff1 + c1) ----
  {
    const f32x4 bi0 = {bb0l1, bb0l1, bb0l1, bb0l1};
    const f32x4 bi1 = {bb1l1, bb1l1, bb1l1, bb1l1};
#define L1G(P0, P1, TF0, TF1)                                                \
    {                                                                        \
      f32x4 c0 = MF(P0, m100, bi0); c0 = MF(P1, m110, c0);                   \
      f32x4 c1 = MF(P0, m101, bi1); c1 = MF(P1, m111, c1);                   \
      TF0 = relupk(c0); TF1 = relupk(c1);                                    \
    }
    L1G(pf00, pf10, tf00, tf01) L1G(pf01, pf11, tf10, tf11)
    L1G(pf02, pf12, tf20, tf21) L1G(pf03, pf13, tf30, tf31)
    L1G(pf04, pf14, tf40, tf41) L1G(pf05, pf15, tf50, tf51)
    L1G(pf06, pf16, tf60, tf61) L1G(pf07, pf17, tf70, tf71)
#undef L1G
  }

  GSTAGE()   // G1
#undef GSTAGE
#undef GP

  // ---- L2 + folded readout ----
  float partial = 0.f;
  {
    const f32x4 bi0 = {bb0l2, bb0l2, bb0l2, bb0l2};
    const f32x4 bi1 = {bb1l2, bb1l2, bb1l2, bb1l2};
#define L2G(g, P0, P1)                                                       \
    {                                                                        \
      f32x4 c0 = MF(P0, m200, bi0); c0 = MF(P1, m210, c0);                   \
      f32x4 c1 = MF(P0, m201, bi1); c1 = MF(P1, m211, c1);                   \
      const float4 vv = *(const float4*)(vl + (g) * 16 + quad * 4);          \
      partial += (fmaxf(c0[0], 0.f) * vv.x + fmaxf(c0[1], 0.f) * vv.y +      \
                  fmaxf(c0[2], 0.f) * vv.z + fmaxf(c0[3], 0.f) * vv.w) * u0 +\
                 (fmaxf(c1[0], 0.f) * vv.x + fmaxf(c1[1], 0.f) * vv.y +      \
                  fmaxf(c1[2], 0.f) * vv.z + fmaxf(c1[3], 0.f) * vv.w) * u1; \
    }
    L2G(0, pf00, pf10) L2G(1, pf01, pf11) L2G(2, pf02, pf12) L2G(3, pf03, pf13)
    L2G(4, pf04, pf14) L2G(5, pf05, pf15) L2G(6, pf06, pf16) L2G(7, pf07, pf17)
#undef L2G
  }
#pragma unroll
  for (int off = 32; off > 0; off >>= 1) partial += __shfl_down(partial, off, 64);
  if (lane == 0) {
    float c2r = 0.f;
    for (int k = 0; k < H; ++k) c2r += b2[2 * H + k] * W_ro[k];
    float S = 0.f;
    for (int j = 0; j < N; ++j) S += vl[j];
    out[b] = partial + c2r * S + b_ro[0];
  }
}

extern "C" void kernel_launch(void* const* d_in, const int* in_sizes, int n_in,
                              void* d_out, int out_size, void* d_ws, size_t ws_size,
                              hipStream_t stream) {
  const float* x      = (const float*)d_in[0];
  const float* adj    = (const float*)d_in[1];
  const float* W_lift = (const float*)d_in[2];
  const float* b_lift = (const float*)d_in[3];
  const float* W1     = (const float*)d_in[4];
  const float* b1     = (const float*)d_in[5];
  const float* W2     = (const float*)d_in[6];
  const float* b2     = (const float*)d_in[7];
  const float* W_ro   = (const float*)d_in[8];
  const float* b_ro   = (const float*)d_in[9];
  float* o = (float*)d_out;

  const int B = in_sizes[0] / (N * 3);   // 16384
  hipLaunchKernelGGL(gnn_fused, dim3(B / 4), dim3(256), 0, stream,
                     x, adj, W_lift, b_lift, W1, b1, W2, b2, W_ro, b_ro, o);
}

// Round 20
// 189.377 us; speedup vs baseline: 1.2497x; 1.2497x over previous
//
#include <hip/hip_runtime.h>

// GNN surrogate — HYBRID chain (r20): K32 MFMAs for G-stages (via wave-private
// LDS T-buffer, r14's verified layout), K16 register-resident L-stages
// (r15-r18's verified C-frag<->operand identity). Rationale: measured
// 3.9 cyc/instr for BOTH 16x16x16 and 16x16x32 -> K16 G wasted half the
// matrix pipe. MFMA/batch: 336 K16 -> 16 K16 + 128 K32 + 64 K16 = 208 instr.
// No barriers: T slab is wave-private; in-wave lgkmcnt orders write->read.
// Folds (exact): M_l = W2[l]@W1[l+1] (adj row-normalized -> biases commute
// through aggregation), lift into W1eff (K=3 pad 16), v=colmean(adj),
// u=W2[2]@W_ro, cp=(b2[2]·W_ro)*sum(v)+b_ro.

typedef _Float16 f16;
typedef __attribute__((ext_vector_type(8))) _Float16 half8;
typedef __attribute__((ext_vector_type(4))) _Float16 half4;
typedef __attribute__((ext_vector_type(2))) __fp16 fp16x2;
typedef __attribute__((ext_vector_type(4))) float f32x4;

namespace {
constexpr int N = 128, H = 32;
constexpr int WS_ADJF = 0;       // f16 [128][128] adj row-major (32768 B)
constexpr int WS_W0B  = 32768;   // f16 [2t][64lane][4] W1eff K16-B tiles (1024 B)
constexpr int WS_MB   = 33792;   // f16 [2l][2t][2tp][64][4] Meff K16-B tiles (4096 B)
constexpr int WS_BIAS = 37888;   // f32 [3][32]
constexpr int WS_V    = 38400;   // f32 [128]
constexpr int WS_U    = 38912;   // f32 [32]
constexpr int WS_C    = 39040;   // f32 [1]
constexpr int TS2 = 136;         // T^T row stride in f16 (272 B = 16*17)
}

static __device__ __forceinline__ half4 pk4(float a, float b, float c, float d) {
  union { half4 v; fp16x2 h[2]; } u;
  u.h[0] = __builtin_amdgcn_cvt_pkrtz(a, b);
  u.h[1] = __builtin_amdgcn_cvt_pkrtz(c, d);
  return u.v;
}
static __device__ __forceinline__ half4 relupk(f32x4 c) {
  const half4 z = {};
  return __builtin_elementwise_max(pk4(c[0], c[1], c[2], c[3]), z);
}
static __device__ __forceinline__ half4 pkc(f32x4 c) {
  return pk4(c[0], c[1], c[2], c[3]);
}

#define MF(A, B, C)  __builtin_amdgcn_mfma_f32_16x16x16f16((A), (B), (C), 0, 0, 0)
#define MF8(A, B, C) __builtin_amdgcn_mfma_f32_16x16x32_f16((A), (B), (C), 0, 0, 0)

// ---- single-block prep ----
__global__ void prep(const float* __restrict__ adj,
                     const float* __restrict__ W_lift,
                     const float* __restrict__ b_lift,
                     const float* __restrict__ W1,
                     const float* __restrict__ b1,
                     const float* __restrict__ W2,
                     const float* __restrict__ b2,
                     const float* __restrict__ W_ro,
                     const float* __restrict__ b_ro,
                     char* __restrict__ ws) {
  const int tid = threadIdx.x;
  f16* adjf  = (f16*)(ws + WS_ADJF);
  f16* w0b   = (f16*)(ws + WS_W0B);
  f16* mb    = (f16*)(ws + WS_MB);
  float* bia = (float*)(ws + WS_BIAS);
  float* v   = (float*)(ws + WS_V);
  float* u   = (float*)(ws + WS_U);
  float* cp  = (float*)(ws + WS_C);

  // adj -> f16 row-major, vectorized
  {
    const float4* a4 = (const float4*)adj;
#pragma unroll
    for (int r = 0; r < 8; ++r) {
      const int idx = r * 512 + tid * 2;
      const float4 p = a4[idx], q = a4[idx + 1];
      *(half4*)(adjf + idx * 4)     = pk4(p.x, p.y, p.z, p.w);
      *(half4*)(adjf + idx * 4 + 4) = pk4(q.x, q.y, q.z, q.w);
    }
  }

  __shared__ float tmp[3][H][H];
  __shared__ float sred[N];
  for (int idx = tid; idx < 3 * H * H; idx += 256) {
    const int l = idx >> 10, rem = idx & 1023;
    const int k = rem >> 5, fo = rem & 31;
    float val = 0.f;
    if (l == 0) {
      if (k < 3) for (int c = 0; c < H; ++c) val += W_lift[k * H + c] * W1[c * H + fo];
    } else {
      const float* w2l = W2 + (l - 1) * H * H;
      const float* w1n = W1 + l * H * H;
      for (int c = 0; c < H; ++c) val += w2l[k * H + c] * w1n[c * H + fo];
    }
    tmp[l][k][fo] = val;
  }
  if (tid < N) {
    float s = 0.f;
    for (int i = 0; i < N; ++i) s += adj[i * N + tid];
    v[tid] = s * (1.0f / N);
    sred[tid] = s * (1.0f / N);
  }
  if (tid < H) {
    float s0 = b1[tid], s1 = b1[H + tid], s2 = b1[2 * H + tid];
    for (int c = 0; c < H; ++c) {
      s0 += b_lift[c] * W1[c * H + tid];
      s1 += b2[c] * W1[H * H + c * H + tid];
      s2 += b2[H + c] * W1[2 * H * H + c * H + tid];
    }
    bia[tid] = s0; bia[H + tid] = s1; bia[2 * H + tid] = s2;
    float su = 0.f;
    for (int c = 0; c < H; ++c) su += W2[2 * H * H + tid * H + c] * W_ro[c];
    u[tid] = su;
  }
  __syncthreads();
  // K16 B-operand layouts (verified r15-r18)
  for (int e = tid; e < 512; e += 256) {
    const int t = e >> 8, lane = (e >> 2) & 63, j = e & 3;
    const int lr = lane & 15, q = lane >> 4;
    w0b[e] = (f16)tmp[0][q * 4 + j][t * 16 + lr];
  }
  for (int e = tid; e < 2048; e += 256) {
    const int l = e >> 10, rem = e & 1023;
    const int t = rem >> 9, tp = (rem >> 8) & 1, lane = (rem >> 2) & 63, j = rem & 3;
    const int lr = lane & 15, q = lane >> 4;
    mb[e] = (f16)tmp[1 + l][t * 16 + q * 4 + j][tp * 16 + lr];
  }
  if (tid == 0) {
    float c2r = 0.f;
    for (int k = 0; k < H; ++k) c2r += b2[2 * H + k] * W_ro[k];
    float S = 0.f;
    for (int j = 0; j < N; ++j) S += sred[j];
    cp[0] = c2r * S + b_ro[0];
  }
}

__global__ __launch_bounds__(256, 2)
void gnn_mfma(const float* __restrict__ x,
              const char* __restrict__ ws,
              float* __restrict__ out) {
  __shared__ __align__(16) f16 Tl[4][32 * TS2];   // 4 wave-private T^T slabs

  const f16* adjf  = (const f16*)(ws + WS_ADJF);
  const f16* w0b   = (const f16*)(ws + WS_W0B);
  const f16* mb    = (const f16*)(ws + WS_MB);
  const float* bia = (const float*)(ws + WS_BIAS);
  const float* v   = (const float*)(ws + WS_V);
  const float* u   = (const float*)(ws + WS_U);
  const float* cp  = (const float*)(ws + WS_C);

  const int tid  = threadIdx.x;
  const int wave = tid >> 6;
  const int lane = tid & 63;
  const int lrow = lane & 15;
  const int quad = lane >> 4;
  const int b    = blockIdx.x * 4 + wave;

  f16* T = &Tl[wave][0];
  const f32x4 zero = {0.f, 0.f, 0.f, 0.f};

  // hoisted weights/biases (fits 256-reg budget; r17-verified layouts)
  const half4 w0   = *(const half4*)(w0b + (0 * 64 + lane) * 4);
  const half4 w1   = *(const half4*)(w0b + (1 * 64 + lane) * 4);
  const half4 m100 = *(const half4*)(mb + ((0 * 4 + 0 * 2 + 0) * 64 + lane) * 4);
  const half4 m101 = *(const half4*)(mb + ((0 * 4 + 0 * 2 + 1) * 64 + lane) * 4);
  const half4 m110 = *(const half4*)(mb + ((0 * 4 + 1 * 2 + 0) * 64 + lane) * 4);
  const half4 m111 = *(const half4*)(mb + ((0 * 4 + 1 * 2 + 1) * 64 + lane) * 4);
  const half4 m200 = *(const half4*)(mb + ((1 * 4 + 0 * 2 + 0) * 64 + lane) * 4);
  const half4 m201 = *(const half4*)(mb + ((1 * 4 + 0 * 2 + 1) * 64 + lane) * 4);
  const half4 m210 = *(const half4*)(mb + ((1 * 4 + 1 * 2 + 0) * 64 + lane) * 4);
  const half4 m211 = *(const half4*)(mb + ((1 * 4 + 1 * 2 + 1) * 64 + lane) * 4);
  const float bb0l0 = bia[lrow],          bb1l0 = bia[16 + lrow];
  const float bb0l1 = bia[H + lrow],      bb1l1 = bia[H + 16 + lrow];
  const float bb0l2 = bia[2 * H + lrow],  bb1l2 = bia[2 * H + 16 + lrow];
  const float u0 = u[lrow], u1 = u[16 + lrow];

  // G output frags (rows=f, cols=node_i), register-resident
  half4 pf00, pf01, pf02, pf03, pf04, pf05, pf06, pf07,
        pf10, pf11, pf12, pf13, pf14, pf15, pf16, pf17;

  // ---- L0: T0[node][f] = relu(x·W1eff + b0eff); C-frag half4 -> T^T[f][node]
  {
    const f32x4 bi0 = {bb0l0, bb0l0, bb0l0, bb0l0};
    const f32x4 bi1 = {bb1l0, bb1l0, bb1l0, bb1l0};
#pragma unroll
    for (int g = 0; g < 8; ++g) {
      half4 xa = {};
      if (quad == 0) {
        const float* xr = x + ((size_t)b * N + g * 16 + lrow) * 3;
        xa = pk4(xr[0], xr[1], xr[2], 0.f);
      }
      const f32x4 c0 = MF(xa, w0, bi0);
      const f32x4 c1 = MF(xa, w1, bi1);
      *(half4*)(T + lrow * TS2 + g * 16 + quad * 4)        = relupk(c0);
      *(half4*)(T + (16 + lrow) * TS2 + g * 16 + quad * 4) = relupk(c1);
    }
  }

  // ---- G stage (K32): P^T[f][i] = sum_j T^T[f][j]·adj[i][j] ----
  // A = T^T half8 from LDS [m=f=lrow][k=node=kt*32+quad*8];
  // B = adjf row-major half8: B[k=j][n=i] (r14-verified orientation).
#define GSTAGE()                                                             \
  {                                                                          \
    const half8 aT00 = *(const half8*)(T + lrow * TS2 + 0 * 32 + quad * 8);  \
    const half8 aT01 = *(const half8*)(T + lrow * TS2 + 1 * 32 + quad * 8);  \
    const half8 aT02 = *(const half8*)(T + lrow * TS2 + 2 * 32 + quad * 8);  \
    const half8 aT03 = *(const half8*)(T + lrow * TS2 + 3 * 32 + quad * 8);  \
    const half8 aT10 = *(const half8*)(T + (16 + lrow) * TS2 + 0 * 32 + quad * 8); \
    const half8 aT11 = *(const half8*)(T + (16 + lrow) * TS2 + 1 * 32 + quad * 8); \
    const half8 aT12 = *(const half8*)(T + (16 + lrow) * TS2 + 2 * 32 + quad * 8); \
    const half8 aT13 = *(const half8*)(T + (16 + lrow) * TS2 + 3 * 32 + quad * 8); \
    GS(0, pf00, pf10) GS(1, pf01, pf11) GS(2, pf02, pf12) GS(3, pf03, pf13)  \
    GS(4, pf04, pf14) GS(5, pf05, pf15) GS(6, pf06, pf16) GS(7, pf07, pf17)  \
  }
#define GS(gi, P0, P1)                                                       \
  {                                                                          \
    const f16* ar = adjf + ((gi) * 16 + lrow) * N + quad * 8;                \
    const half8 bf0 = *(const half8*)(ar + 0 * 32);                          \
    const half8 bf1 = *(const half8*)(ar + 1 * 32);                          \
    const half8 bf2 = *(const half8*)(ar + 2 * 32);                          \
    const half8 bf3 = *(const half8*)(ar + 3 * 32);                          \
    f32x4 a0 = zero, a1 = zero;                                              \
    a0 = MF8(aT00, bf0, a0); a1 = MF8(aT10, bf0, a1);                        \
    a0 = MF8(aT01, bf1, a0); a1 = MF8(aT11, bf1, a1);                        \
    a0 = MF8(aT02, bf2, a0); a1 = MF8(aT12, bf2, a1);                        \
    a0 = MF8(aT03, bf3, a0); a1 = MF8(aT13, bf3, a1);                        \
    P0 = pkc(a0); P1 = pkc(a1);                                              \
  }

  GSTAGE()   // G0

  // ---- L1 (K16): T1[node][f'] = relu(P·Meff1 + c1); pf as A (= P, contracts f)
  {
    const f32x4 bi0 = {bb0l1, bb0l1, bb0l1, bb0l1};
    const f32x4 bi1 = {bb1l1, bb1l1, bb1l1, bb1l1};
#define L1G(g, P0, P1)                                                       \
    {                                                                        \
      f32x4 c0 = MF(P0, m100, bi0); c0 = MF(P1, m110, c0);                   \
      f32x4 c1 = MF(P0, m101, bi1); c1 = MF(P1, m111, c1);                   \
      *(half4*)(T + lrow * TS2 + (g) * 16 + quad * 4)        = relupk(c0);   \
      *(half4*)(T + (16 + lrow) * TS2 + (g) * 16 + quad * 4) = relupk(c1);   \
    }
    L1G(0, pf00, pf10) L1G(1, pf01, pf11) L1G(2, pf02, pf12) L1G(3, pf03, pf13)
    L1G(4, pf04, pf14) L1G(5, pf05, pf15) L1G(6, pf06, pf16) L1G(7, pf07, pf17)
#undef L1G
  }

  GSTAGE()   // G1
#undef GSTAGE
#undef GS

  // ---- L2 (K16) + folded readout ----
  float partial = 0.f;
  {
    const f32x4 bi0 = {bb0l2, bb0l2, bb0l2, bb0l2};
    const f32x4 bi1 = {bb1l2, bb1l2, bb1l2, bb1l2};
#define L2G(g, P0, P1)                                                       \
    {                                                                        \
      f32x4 c0 = MF(P0, m200, bi0); c0 = MF(P1, m210, c0);                   \
      f32x4 c1 = MF(P0, m201, bi1); c1 = MF(P1, m211, c1);                   \
      const float4 vv = *(const float4*)(v + (g) * 16 + quad * 4);           \
      partial += (fmaxf(c0[0], 0.f) * vv.x + fmaxf(c0[1], 0.f) * vv.y +      \
                  fmaxf(c0[2], 0.f) * vv.z + fmaxf(c0[3], 0.f) * vv.w) * u0 +\
                 (fmaxf(c1[0], 0.f) * vv.x + fmaxf(c1[1], 0.f) * vv.y +      \
                  fmaxf(c1[2], 0.f) * vv.z + fmaxf(c1[3], 0.f) * vv.w) * u1; \
    }
    L2G(0, pf00, pf10) L2G(1, pf01, pf11) L2G(2, pf02, pf12) L2G(3, pf03, pf13)
    L2G(4, pf04, pf14) L2G(5, pf05, pf15) L2G(6, pf06, pf16) L2G(7, pf07, pf17)
#undef L2G
  }
#pragma unroll
  for (int off = 32; off > 0; off >>= 1) partial += __shfl_down(partial, off, 64);
  if (lane == 0) out[b] = partial + cp[0];
}

extern "C" void kernel_launch(void* const* d_in, const int* in_sizes, int n_in,
                              void* d_out, int out_size, void* d_ws, size_t ws_size,
                              hipStream_t stream) {
  const float* x      = (const float*)d_in[0];
  const float* adj    = (const float*)d_in[1];
  const float* W_lift = (const float*)d_in[2];
  const float* b_lift = (const float*)d_in[3];
  const float* W1     = (const float*)d_in[4];
  const float* b1     = (const float*)d_in[5];
  const float* W2     = (const float*)d_in[6];
  const float* b2     = (const float*)d_in[7];
  const float* W_ro   = (const float*)d_in[8];
  const float* b_ro   = (const float*)d_in[9];
  char* ws = (char*)d_ws;
  float* o = (float*)d_out;

  const int B = in_sizes[0] / (N * 3);   // 16384
  hipLaunchKernelGGL(prep, dim3(1), dim3(256), 0, stream,
                     adj, W_lift, b_lift, W1, b1, W2, b2, W_ro, b_ro, ws);
  hipLaunchKernelGGL(gnn_mfma, dim3(B / 4), dim3(256), 0, stream,
                     x, (const char*)ws, o);
}

// Round 21
// 171.822 us; speedup vs baseline: 1.3774x; 1.1022x over previous
//
#include <hip/hip_runtime.h>

// GNN surrogate — r17 all-register K16 chain x TWO batches per wave (r21).
// r17 (93 us) issue audit: ~1400 issue-cyc/wave vs 93 us observed -> ~75%
// dependency stall at 2 waves/SIMD; occupancy is register-capped, so add
// in-wave concurrency instead (r12 precedent: +1 batch/wave = 1.33x).
// Stages interleaved L0AB,G0A,G0B,L1AB,G1A,G1B,L2AB; the two G-stages are
// kept sequential so only one 64-AGPR acc set is live at a time.
// Layout identity (verified r15-r18): mfma_f32_16x16x16f16 C-frag
// [row=quad*4+r][col=lane&15] == operand [k=quad*4+j][m|n=lane&15]; a pk4'd
// C-frag IS the next stage's operand. Zero LDS, zero barriers.
// Folds (exact): M_l = W2[l]@W1[l+1], lift into W1eff (K=3 pad 16), v, u, cp.

typedef _Float16 f16;
typedef __attribute__((ext_vector_type(4))) _Float16 half4;
typedef __attribute__((ext_vector_type(2))) __fp16 fp16x2;
typedef __attribute__((ext_vector_type(4))) float f32x4;

namespace {
constexpr int N = 128, H = 32;
constexpr int WS_ADJB = 0;       // f16 swizzled adj tiles [8g][4p][64lane][8] (32768 B)
constexpr int WS_W0B  = 32768;   // f16 [2t][64lane][4]  W1eff B-tiles        (1024 B)
constexpr int WS_MB   = 33792;   // f16 [2l][2t][2tp][64][4] Meff B-tiles     (4096 B)
constexpr int WS_BIAS = 37888;   // f32 [3][32]
constexpr int WS_V    = 38400;   // f32 [128]
constexpr int WS_U    = 38912;   // f32 [32]
constexpr int WS_C    = 39040;   // f32 [1]
}

static __device__ __forceinline__ half4 pk4(float a, float b, float c, float d) {
  union { half4 v; fp16x2 h[2]; } u;
  u.h[0] = __builtin_amdgcn_cvt_pkrtz(a, b);
  u.h[1] = __builtin_amdgcn_cvt_pkrtz(c, d);
  return u.v;
}
static __device__ __forceinline__ half4 relupk(f32x4 c) {
  const half4 z = {};
  return __builtin_elementwise_max(pk4(c[0], c[1], c[2], c[3]), z);
}
static __device__ __forceinline__ half4 pkc(f32x4 c) {
  return pk4(c[0], c[1], c[2], c[3]);
}

#define MF(A, B, C) __builtin_amdgcn_mfma_f32_16x16x16f16((A), (B), (C), 0, 0, 0)

// ---- prep: identical to r15-r18 (verified) ----
__global__ void prep(const float* __restrict__ adj,
                     const float* __restrict__ W_lift,
                     const float* __restrict__ b_lift,
                     const float* __restrict__ W1,
                     const float* __restrict__ b1,
                     const float* __restrict__ W2,
                     const float* __restrict__ b2,
                     const float* __restrict__ W_ro,
                     const float* __restrict__ b_ro,
                     char* __restrict__ ws) {
  const int tid = threadIdx.x;
  f16* adjb  = (f16*)(ws + WS_ADJB);
  f16* w0b   = (f16*)(ws + WS_W0B);
  f16* mb    = (f16*)(ws + WS_MB);
  float* bia = (float*)(ws + WS_BIAS);
  float* v   = (float*)(ws + WS_V);
  float* u   = (float*)(ws + WS_U);
  float* cp  = (float*)(ws + WS_C);

  for (int e = tid; e < 2048; e += 256) {
    const int g = e >> 8, p = (e >> 6) & 3, lane = e & 63;
    const int lr = lane & 15, q = lane >> 4;
    const float* src = adj + (g * 16 + lr) * N;
    f16* dst = adjb + e * 8;
#pragma unroll
    for (int h = 0; h < 2; ++h)
#pragma unroll
      for (int jj = 0; jj < 4; ++jj)
        dst[h * 4 + jj] = (f16)src[(2 * p + h) * 16 + q * 4 + jj];
  }

  __shared__ float tmp[3][H][H];
  __shared__ float sred[N];
  for (int idx = tid; idx < 3 * H * H; idx += 256) {
    const int l = idx >> 10, rem = idx & 1023;
    const int k = rem >> 5, fo = rem & 31;
    float val = 0.f;
    if (l == 0) {
      if (k < 3) for (int c = 0; c < H; ++c) val += W_lift[k * H + c] * W1[c * H + fo];
    } else {
      const float* w2l = W2 + (l - 1) * H * H;
      const float* w1n = W1 + l * H * H;
      for (int c = 0; c < H; ++c) val += w2l[k * H + c] * w1n[c * H + fo];
    }
    tmp[l][k][fo] = val;
  }
  if (tid < N) {
    float s = 0.f;
    for (int i = 0; i < N; ++i) s += adj[i * N + tid];
    v[tid] = s * (1.0f / N);
    sred[tid] = s * (1.0f / N);
  }
  if (tid < H) {
    float s0 = b1[tid], s1 = b1[H + tid], s2 = b1[2 * H + tid];
    for (int c = 0; c < H; ++c) {
      s0 += b_lift[c] * W1[c * H + tid];
      s1 += b2[c] * W1[H * H + c * H + tid];
      s2 += b2[H + c] * W1[2 * H * H + c * H + tid];
    }
    bia[tid] = s0; bia[H + tid] = s1; bia[2 * H + tid] = s2;
    float su = 0.f;
    for (int c = 0; c < H; ++c) su += W2[2 * H * H + tid * H + c] * W_ro[c];
    u[tid] = su;
  }
  __syncthreads();
  for (int e = tid; e < 512; e += 256) {
    const int t = e >> 8, lane = (e >> 2) & 63, j = e & 3;
    const int lr = lane & 15, q = lane >> 4;
    w0b[e] = (f16)tmp[0][q * 4 + j][t * 16 + lr];
  }
  for (int e = tid; e < 2048; e += 256) {
    const int l = e >> 10, rem = e & 1023;
    const int t = rem >> 9, tp = (rem >> 8) & 1, lane = (rem >> 2) & 63, j = rem & 3;
    const int lr = lane & 15, q = lane >> 4;
    mb[e] = (f16)tmp[1 + l][t * 16 + q * 4 + j][tp * 16 + lr];
  }
  if (tid == 0) {
    float c2r = 0.f;
    for (int k = 0; k < H; ++k) c2r += b2[2 * H + k] * W_ro[k];
    float S = 0.f;
    for (int j = 0; j < N; ++j) S += sred[j];
    cp[0] = c2r * S + b_ro[0];
  }
}

__global__ __launch_bounds__(256, 2)
void gnn_mfma(const float* __restrict__ x,
              const char* __restrict__ ws,
              float* __restrict__ out) {
  const f16* adjb  = (const f16*)(ws + WS_ADJB);
  const f16* w0b   = (const f16*)(ws + WS_W0B);
  const f16* mb    = (const f16*)(ws + WS_MB);
  const float* bia = (const float*)(ws + WS_BIAS);
  const float* v   = (const float*)(ws + WS_V);
  const float* u   = (const float*)(ws + WS_U);
  const float* cp  = (const float*)(ws + WS_C);

  const int tid  = threadIdx.x;
  const int wave = tid >> 6;
  const int lane = tid & 63;
  const int lrow = lane & 15;
  const int quad = lane >> 4;
  const int bA   = blockIdx.x * 8 + wave * 2;
  const int bB   = bA + 1;

  const f32x4 zero = {0.f, 0.f, 0.f, 0.f};

  half4 tfA00, tfA01, tfA10, tfA11, tfA20, tfA21, tfA30, tfA31,
        tfA40, tfA41, tfA50, tfA51, tfA60, tfA61, tfA70, tfA71;
  half4 tfB00, tfB01, tfB10, tfB11, tfB20, tfB21, tfB30, tfB31,
        tfB40, tfB41, tfB50, tfB51, tfB60, tfB61, tfB70, tfB71;
  half4 pfA00, pfA01, pfA02, pfA03, pfA04, pfA05, pfA06, pfA07,
        pfA10, pfA11, pfA12, pfA13, pfA14, pfA15, pfA16, pfA17;
  half4 pfB00, pfB01, pfB02, pfB03, pfB04, pfB05, pfB06, pfB07,
        pfB10, pfB11, pfB12, pfB13, pfB14, pfB15, pfB16, pfB17;

  // ---- L0 (both batches, interleaved) ----
  {
    const half4 w0 = *(const half4*)(w0b + (0 * 64 + lane) * 4);
    const half4 w1 = *(const half4*)(w0b + (1 * 64 + lane) * 4);
    const float bb0 = bia[lrow], bb1 = bia[16 + lrow];
    const f32x4 bi0 = {bb0, bb0, bb0, bb0};
    const f32x4 bi1 = {bb1, bb1, bb1, bb1};
#define L0G(BIDX, g, TF0, TF1)                                               \
    {                                                                        \
      half4 xa = {};                                                         \
      if (quad == 0) {                                                       \
        const float* xr = x + ((size_t)(BIDX) * N + (g) * 16 + lrow) * 3;    \
        xa = pk4(xr[0], xr[1], xr[2], 0.f);                                  \
      }                                                                      \
      TF0 = relupk(MF(xa, w0, bi0));                                         \
      TF1 = relupk(MF(xa, w1, bi1));                                         \
    }
    L0G(bA, 0, tfA00, tfA01) L0G(bB, 0, tfB00, tfB01)
    L0G(bA, 1, tfA10, tfA11) L0G(bB, 1, tfB10, tfB11)
    L0G(bA, 2, tfA20, tfA21) L0G(bB, 2, tfB20, tfB21)
    L0G(bA, 3, tfA30, tfA31) L0G(bB, 3, tfB30, tfB31)
    L0G(bA, 4, tfA40, tfA41) L0G(bB, 4, tfB40, tfB41)
    L0G(bA, 5, tfA50, tfA51) L0G(bB, 5, tfB50, tfB51)
    L0G(bA, 6, tfA60, tfA61) L0G(bB, 6, tfB60, tfB61)
    L0G(bA, 7, tfA70, tfA71) L0G(bB, 7, tfB70, tfB71)
#undef L0G
  }

  // ---- G stage (per batch S): 16 independent chains, r17 GSTEP ----
#define GSTEP(S, gi, P0, P1)                                                 \
  {                                                                          \
    f32x4 a0 = zero, a1 = zero;                                              \
    const f16* ab = adjb + (((gi) * 4) * 64 + lane) * 8;                     \
    half4 h0 = *(const half4*)(ab + 0 * 512 + 0);                            \
    half4 h1 = *(const half4*)(ab + 0 * 512 + 4);                            \
    a0 = MF(tf##S##00, h0, a0); a1 = MF(tf##S##01, h0, a1);                  \
    a0 = MF(tf##S##10, h1, a0); a1 = MF(tf##S##11, h1, a1);                  \
    h0 = *(const half4*)(ab + 1 * 512 + 0);                                  \
    h1 = *(const half4*)(ab + 1 * 512 + 4);                                  \
    a0 = MF(tf##S##20, h0, a0); a1 = MF(tf##S##21, h0, a1);                  \
    a0 = MF(tf##S##30, h1, a0); a1 = MF(tf##S##31, h1, a1);                  \
    h0 = *(const half4*)(ab + 2 * 512 + 0);                                  \
    h1 = *(const half4*)(ab + 2 * 512 + 4);                                  \
    a0 = MF(tf##S##40, h0, a0); a1 = MF(tf##S##41, h0, a1);                  \
    a0 = MF(tf##S##50, h1, a0); a1 = MF(tf##S##51, h1, a1);                  \
    h0 = *(const half4*)(ab + 3 * 512 + 0);                                  \
    h1 = *(const half4*)(ab + 3 * 512 + 4);                                  \
    a0 = MF(tf##S##60, h0, a0); a1 = MF(tf##S##61, h0, a1);                  \
    a0 = MF(tf##S##70, h1, a0); a1 = MF(tf##S##71, h1, a1);                  \
    P0 = pkc(a0); P1 = pkc(a1);                                              \
  }
#define GSTAGE(S)                                                            \
  GSTEP(S, 0, pf##S##00, pf##S##10) GSTEP(S, 1, pf##S##01, pf##S##11)        \
  GSTEP(S, 2, pf##S##02, pf##S##12) GSTEP(S, 3, pf##S##03, pf##S##13)        \
  GSTEP(S, 4, pf##S##04, pf##S##14) GSTEP(S, 5, pf##S##05, pf##S##15)        \
  GSTEP(S, 6, pf##S##06, pf##S##16) GSTEP(S, 7, pf##S##07, pf##S##17)

  GSTAGE(A)   // G0 batch A
  GSTAGE(B)   // G0 batch B

  // ---- L1 (both batches, interleaved) ----
  {
    const f16* mbl = mb + 0 * 1024;
    const half4 m00 = *(const half4*)(mbl + ((0 * 2 + 0) * 64 + lane) * 4);
    const half4 m01 = *(const half4*)(mbl + ((0 * 2 + 1) * 64 + lane) * 4);
    const half4 m10 = *(const half4*)(mbl + ((1 * 2 + 0) * 64 + lane) * 4);
    const half4 m11 = *(const half4*)(mbl + ((1 * 2 + 1) * 64 + lane) * 4);
    const float bb0 = bia[H + lrow], bb1 = bia[H + 16 + lrow];
    const f32x4 bi0 = {bb0, bb0, bb0, bb0};
    const f32x4 bi1 = {bb1, bb1, bb1, bb1};
#define L1G(P0, P1, TF0, TF1)                                                \
    {                                                                        \
      f32x4 c0 = MF(P0, m00, bi0); c0 = MF(P1, m10, c0);                     \
      f32x4 c1 = MF(P0, m01, bi1); c1 = MF(P1, m11, c1);                     \
      TF0 = relupk(c0); TF1 = relupk(c1);                                    \
    }
    L1G(pfA00, pfA10, tfA00, tfA01) L1G(pfB00, pfB10, tfB00, tfB01)
    L1G(pfA01, pfA11, tfA10, tfA11) L1G(pfB01, pfB11, tfB10, tfB11)
    L1G(pfA02, pfA12, tfA20, tfA21) L1G(pfB02, pfB12, tfB20, tfB21)
    L1G(pfA03, pfA13, tfA30, tfA31) L1G(pfB03, pfB13, tfB30, tfB31)
    L1G(pfA04, pfA14, tfA40, tfA41) L1G(pfB04, pfB14, tfB40, tfB41)
    L1G(pfA05, pfA15, tfA50, tfA51) L1G(pfB05, pfB15, tfB50, tfB51)
    L1G(pfA06, pfA16, tfA60, tfA61) L1G(pfB06, pfB16, tfB60, tfB61)
    L1G(pfA07, pfA17, tfA70, tfA71) L1G(pfB07, pfB17, tfB70, tfB71)
#undef L1G
  }

  GSTAGE(A)   // G1 batch A
  GSTAGE(B)   // G1 batch B
#undef GSTAGE
#undef GSTEP

  // ---- L2 + folded readout (both batches) ----
  float pAcc = 0.f, pBcc = 0.f;
  {
    const f16* mbl = mb + 1 * 1024;
    const half4 m00 = *(const half4*)(mbl + ((0 * 2 + 0) * 64 + lane) * 4);
    const half4 m01 = *(const half4*)(mbl + ((0 * 2 + 1) * 64 + lane) * 4);
    const half4 m10 = *(const half4*)(mbl + ((1 * 2 + 0) * 64 + lane) * 4);
    const half4 m11 = *(const half4*)(mbl + ((1 * 2 + 1) * 64 + lane) * 4);
    const float bb0 = bia[2 * H + lrow], bb1 = bia[2 * H + 16 + lrow];
    const f32x4 bi0 = {bb0, bb0, bb0, bb0};
    const f32x4 bi1 = {bb1, bb1, bb1, bb1};
    const float u0 = u[lrow], u1 = u[16 + lrow];
#define L2G(g, P0, P1, ACC)                                                  \
    {                                                                        \
      f32x4 c0 = MF(P0, m00, bi0); c0 = MF(P1, m10, c0);                     \
      f32x4 c1 = MF(P0, m01, bi1); c1 = MF(P1, m11, c1);                     \
      const float4 vv = *(const float4*)(v + (g) * 16 + quad * 4);           \
      ACC += (fmaxf(c0[0], 0.f) * vv.x + fmaxf(c0[1], 0.f) * vv.y +          \
              fmaxf(c0[2], 0.f) * vv.z + fmaxf(c0[3], 0.f) * vv.w) * u0 +    \
             (fmaxf(c1[0], 0.f) * vv.x + fmaxf(c1[1], 0.f) * vv.y +          \
              fmaxf(c1[2], 0.f) * vv.z + fmaxf(c1[3], 0.f) * vv.w) * u1;     \
    }
    L2G(0, pfA00, pfA10, pAcc) L2G(0, pfB00, pfB10, pBcc)
    L2G(1, pfA01, pfA11, pAcc) L2G(1, pfB01, pfB11, pBcc)
    L2G(2, pfA02, pfA12, pAcc) L2G(2, pfB02, pfB12, pBcc)
    L2G(3, pfA03, pfA13, pAcc) L2G(3, pfB03, pfB13, pBcc)
    L2G(4, pfA04, pfA14, pAcc) L2G(4, pfB04, pfB14, pBcc)
    L2G(5, pfA05, pfA15, pAcc) L2G(5, pfB05, pfB15, pBcc)
    L2G(6, pfA06, pfA16, pAcc) L2G(6, pfB06, pfB16, pBcc)
    L2G(7, pfA07, pfA17, pAcc) L2G(7, pfB07, pfB17, pBcc)
#undef L2G
  }
#pragma unroll
  for (int off = 32; off > 0; off >>= 1) {
    pAcc += __shfl_down(pAcc, off, 64);
    pBcc += __shfl_down(pBcc, off, 64);
  }
  if (lane == 0) {
    const float c0 = cp[0];
    out[bA] = pAcc + c0;
    out[bB] = pBcc + c0;
  }
}

extern "C" void kernel_launch(void* const* d_in, const int* in_sizes, int n_in,
                              void* d_out, int out_size, void* d_ws, size_t ws_size,
                              hipStream_t stream) {
  const float* x      = (const float*)d_in[0];
  const float* adj    = (const float*)d_in[1];
  const float* W_lift = (const float*)d_in[2];
  const float* b_lift = (const float*)d_in[3];
  const float* W1     = (const float*)d_in[4];
  const float* b1     = (const float*)d_in[5];
  const float* W2     = (const float*)d_in[6];
  const float* b2     = (const float*)d_in[7];
  const float* W_ro   = (const float*)d_in[8];
  const float* b_ro   = (const float*)d_in[9];
  char* ws = (char*)d_ws;
  float* o = (float*)d_out;

  const int B = in_sizes[0] / (N * 3);   // 16384
  hipLaunchKernelGGL(prep, dim3(1), dim3(256), 0, stream,
                     adj, W_lift, b_lift, W1, b1, W2, b2, W_ro, b_ro, ws);
  hipLaunchKernelGGL(gnn_mfma, dim3(B / 8), dim3(256), 0, stream,
                     x, (const char*)ws, o);
}